// Round 3
// baseline (162.379 us; speedup 1.0000x reference)
//
#include <hip/hip_runtime.h>
#include <stdint.h>

using short8 = __attribute__((ext_vector_type(8))) short;
using f32x4  = __attribute__((ext_vector_type(4))) float;
typedef unsigned short u16;
typedef unsigned int   u32;

// ---------- ws layout (bytes) ----------
#define OFF_X    0u           // X_bf16 [4096][224]
#define OFF_W1   1835008u     // W1bf [256][224]
#define OFF_W2   1949696u     // W2bf [256][256]
#define OFF_W3   2080768u     // W3bf [192][256]
#define OFF_BM   2179072u     // Bmat [128][32768] bf16 (permuted WK/WL/bK/bL)
#define OFF_Q    10567680u    // q_g [4096][160] bf16
#define OFF_P    11878400u    // p_g [4096][208] bf16
#define OFF_T1   13582336u    // t1 [4096][256] f32
#define OFF_T2   17776640u    // t2 [4096][256] f32
#define OFF_ST   21970944u    // 4 x 256 f32 stats
#define WS_NEED  21975040u

__device__ __forceinline__ float b2f(u16 u){ u32 x = ((u32)u)<<16; float f; __builtin_memcpy(&f,&x,4); return f; }
__device__ __forceinline__ u16 f2b(float f){ u32 x; __builtin_memcpy(&x,&f,4); u32 r = (x + 0x7FFFu + ((x>>16)&1u))>>16; return (u16)r; }
__device__ __forceinline__ float u2f(u32 x){ float f; __builtin_memcpy(&f,&x,4); return f; }
__device__ __forceinline__ u32 swz64(u32 row){ return ((row ^ (row>>2)) & 3u) << 4; }   // 64B-stride tiles
__device__ __forceinline__ u32 swz512(u32 row){ return (row & 7u) << 4; }               // 512B-stride tiles
__device__ __forceinline__ u32 cvtpk(float lo, float hi){ u32 d; asm("v_cvt_pk_bf16_f32 %0, %1, %2" : "=v"(d) : "v"(lo), "v"(hi)); return d; }

union U16x8 { uint4 u; short8 s; };

// ---------------- prep: X, q, p-tail, W1/2/3 bf16 ----------------
__global__ __launch_bounds__(256) void prep_misc(
    const float* __restrict__ z_dyn, const float* __restrict__ z_static,
    const float* __restrict__ dt, const float* __restrict__ ut,
    const float* __restrict__ W1, const float* __restrict__ W2, const float* __restrict__ W3,
    u16* __restrict__ Xb, u16* __restrict__ qg, u16* __restrict__ pg,
    u16* __restrict__ W1b, u16* __restrict__ W2b, u16* __restrict__ W3b)
{
  const int NX = 4096*224, NQ = 4096*160, NP = 4096*16, NW1 = 256*224, NW2 = 256*256, NW3 = 192*256;
  const int total = NX+NQ+NP+NW1+NW2+NW3;
  for (int i = blockIdx.x*256 + threadIdx.x; i < total; i += gridDim.x*256) {
    int idx = i;
    if (idx < NX) {
      int b = idx / 224, k = idx % 224;
      float v = (k < 128) ? z_dyn[b*128+k] : (k < 192 ? z_static[b*64+(k-128)] : (k == 192 ? dt[b] : 0.f));
      Xb[idx] = f2b(v);
    } else if ((idx -= NX) < NQ) {
      int b = idx / 160, c = idx % 160;
      float v = (c < 128) ? z_dyn[b*128+c] : (c < 144 ? ut[b*16+(c-128)]*dt[b] : 0.f);
      qg[idx] = f2b(v);
    } else if ((idx -= NQ) < NP) {
      int b = idx >> 4, c = idx & 15;   // p cols 192..207
      pg[b*208 + 192 + c] = (c == 0) ? (u16)0x3F80 : (u16)0;   // bias slot = 1.0
    } else if ((idx -= NP) < NW1) {
      int j = idx / 224, k = idx % 224;
      W1b[idx] = f2b(k < 193 ? W1[j*193+k] : 0.f);
    } else if ((idx -= NW1) < NW2) {
      W2b[idx] = f2b(W2[idx]);
    } else { idx -= NW2;
      W3b[idx] = f2b(W3[idx]);
    }
  }
}

// ---------------- prep: permuted big-B panel ----------------
// Bmat[i][a*160+c]: c<128 -> WK[(i*128+c),a]; 128<=c<144 -> WL[(i*16+c-128),a]; a==192 -> bK/bL; else 0
__global__ __launch_bounds__(256) void prep_bmat(
    const float* __restrict__ WK, const float* __restrict__ bK,
    const float* __restrict__ WL, const float* __restrict__ bL, u16* __restrict__ Bm)
{
  int i   = blockIdx.x >> 4;
  int kk0 = (blockIdx.x & 15) * 2048 + threadIdx.x * 8;
  int a = kk0 / 160, c = kk0 % 160;
  u16 v[8];
  #pragma unroll
  for (int e = 0; e < 8; ++e) {
    int ce = c + e; float f = 0.f;
    if (ce < 144 && a <= 192) {
      if (a < 192) f = (ce < 128) ? WK[(i*128+ce)*192 + a] : WL[(i*16+(ce-128))*192 + a];
      else         f = (ce < 128) ? bK[i*128+ce]           : bL[i*16+(ce-128)];
    }
    v[e] = f2b(f);
  }
  *(uint4*)(Bm + i*32768 + kk0) = *(uint4*)v;
}

// ---------------- small MFMA GEMM (MLP layers) ----------------
// BM=128, BN=64, BK=32, 4 waves (2x2), wave tile 64x32 (mf=4,nf=2)
// MODE 0: A = Xb (bf16), out = t1 f32 + b1
// MODE 1: A = BN1(t1)+ReLU -> bf16, out = t2 f32 + b2
// MODE 2: A = BN2(t2)+ReLU -> bf16, out = p_g bf16 (hz + b3)
template<int MODE>
__global__ __launch_bounds__(256) void gemm_mlp(
    const u16* __restrict__ Asrc_bf, const float* __restrict__ Asrc_f,
    const u16* __restrict__ Wb, int kstride, int ksteps,
    const float* __restrict__ S1, const float* __restrict__ S2,
    const float* __restrict__ g, const float* __restrict__ be,
    const float* __restrict__ bias,
    float* __restrict__ out_f, u16* __restrict__ out_b)
{
  __shared__ __align__(16) u16 As[2][128*32];
  __shared__ __align__(16) u16 Bs[2][64*32];
  __shared__ float scale_s[256], shift_s[256];
  const int tid = threadIdx.x, lane = tid & 63, wid = tid >> 6;
  const int wr = wid >> 1, wc = wid & 1;
  const int b0 = blockIdx.x * 128, n0 = blockIdx.y * 64;

  if constexpr (MODE >= 1) {
    float m = S1[tid] * (1.f/4096.f);
    float v = S2[tid] * (1.f/4096.f) - m*m;
    float sc = g[tid] * rsqrtf(v + 1e-5f);
    scale_s[tid] = sc; shift_s[tid] = be[tid] - m*sc;
    __syncthreads();
  }

  uint4 arr[2]; uint4 brr;
  auto loadA = [&](int t){
    int k0 = t*32;
    #pragma unroll
    for (int h = 0; h < 2; ++h) {
      int cI = tid + h*256; int row = cI >> 2, j = cI & 3;
      if constexpr (MODE == 0) {
        arr[h] = *(const uint4*)(Asrc_bf + (b0+row)*224 + k0 + j*8);
      } else {
        const float* src = Asrc_f + (b0+row)*256 + k0 + j*8;
        u32 d[4];
        #pragma unroll
        for (int p = 0; p < 4; ++p) {
          int kA = k0 + j*8 + p*2, kB = kA + 1;
          float h0 = fmaxf(0.f, src[p*2]   * scale_s[kA] + shift_s[kA]);
          float h1 = fmaxf(0.f, src[p*2+1] * scale_s[kB] + shift_s[kB]);
          d[p] = cvtpk(h0, h1);
        }
        arr[h] = make_uint4(d[0], d[1], d[2], d[3]);
      }
    }
  };
  auto loadB = [&](int t){
    int k0 = t*32; int col = tid >> 2, j = tid & 3;
    brr = *(const uint4*)(Wb + (n0+col)*kstride + k0 + j*8);
  };
  auto writeAB = [&](int buf){
    #pragma unroll
    for (int h = 0; h < 2; ++h) {
      int cI = tid + h*256; int row = cI >> 2, j = cI & 3;
      *(uint4*)((char*)As[buf] + row*64 + ((j*16) ^ swz64(row))) = arr[h];
    }
    { int col = tid >> 2, j = tid & 3;
      *(uint4*)((char*)Bs[buf] + col*64 + ((j*16) ^ swz64(col))) = brr; }
  };

  f32x4 acc[4][2];
  #pragma unroll
  for (int i = 0; i < 4; ++i)
    #pragma unroll
    for (int j = 0; j < 2; ++j) acc[i][j] = f32x4{0.f,0.f,0.f,0.f};

  loadA(0); loadB(0); writeAB(0);
  __syncthreads();

  for (int t = 0; t < ksteps; ++t) {
    int buf = t & 1;
    if (t + 1 < ksteps) { loadA(t+1); loadB(t+1); }
    short8 af[4], bfr[2];
    #pragma unroll
    for (int mf = 0; mf < 4; ++mf) {
      u32 row = wr*64 + mf*16 + (lane & 15);
      U16x8 u; u.u = *(const uint4*)((const char*)As[buf] + row*64 + ((16*(lane>>4)) ^ swz64(row)));
      af[mf] = u.s;
    }
    #pragma unroll
    for (int nf = 0; nf < 2; ++nf) {
      u32 col = wc*32 + nf*16 + (lane & 15);
      U16x8 u; u.u = *(const uint4*)((const char*)Bs[buf] + col*64 + ((16*(lane>>4)) ^ swz64(col)));
      bfr[nf] = u.s;
    }
    #pragma unroll
    for (int mf = 0; mf < 4; ++mf)
      #pragma unroll
      for (int nf = 0; nf < 2; ++nf)
        acc[mf][nf] = __builtin_amdgcn_mfma_f32_16x16x32_bf16(af[mf], bfr[nf], acc[mf][nf], 0, 0, 0);
    if (t + 1 < ksteps) writeAB(buf ^ 1);
    __syncthreads();
  }

  float bvals[2];
  #pragma unroll
  for (int nf = 0; nf < 2; ++nf) bvals[nf] = bias[n0 + wc*32 + nf*16 + (lane & 15)];
  #pragma unroll
  for (int mf = 0; mf < 4; ++mf)
    #pragma unroll
    for (int nf = 0; nf < 2; ++nf) {
      int colg = n0 + wc*32 + nf*16 + (lane & 15);
      #pragma unroll
      for (int r = 0; r < 4; ++r) {
        int m = b0 + wr*64 + mf*16 + (lane>>4)*4 + r;
        float v = acc[mf][nf][r] + bvals[nf];
        if constexpr (MODE <= 1) out_f[m*256 + colg] = v;
        else                     out_b[m*208 + colg] = f2b(v);
      }
    }
}

// ---------------- column stats (sum, sumsq) ----------------
__global__ __launch_bounds__(256) void stats_k(const float* __restrict__ t, float* __restrict__ S1, float* __restrict__ S2)
{
  int j = threadIdx.x; int b0 = blockIdx.x * 64;
  float s1 = 0.f, s2 = 0.f;
  for (int r = 0; r < 64; ++r) { float v = t[(b0+r)*256 + j]; s1 += v; s2 += v*v; }
  atomicAdd(&S1[j], s1); atomicAdd(&S2[j], s2);
}

// ---------------- big bilinear GEMM ----------------
// M=4096 (BM=64), N=128, K=32768, SPLITK=8 (chunk 4096), BK=32
// A[b][a*160+c] = p[b][a]*q[b][c] built on the fly; B = Bmat; atomicAdd into zn.
__global__ __launch_bounds__(256) void big_gemm(
    const u16* __restrict__ Bm, const u16* __restrict__ qg, const u16* __restrict__ pg,
    float* __restrict__ zn)
{
  __shared__ __align__(16) u16 q_s[64*256];     // 64 rows x 512B (swizzled)
  __shared__ __align__(16) u16 b_s[2][128*32];  // double-buffered B tile
  const int tid = threadIdx.x, lane = tid & 63, wid = tid >> 6;
  const int wr = wid >> 1, wc = wid & 1;
  const int b0 = blockIdx.x * 64;
  const int kbase = blockIdx.y * 4096;

  for (int cI = tid; cI < 1280; cI += 256) {      // stage q (64 rows x 160 bf16)
    int row = cI / 20, j = cI % 20;
    uint4 v = *(const uint4*)(qg + (b0+row)*160 + j*8);
    *(uint4*)((char*)q_s + row*512 + ((j*16) ^ swz512((u32)row))) = v;
  }

  uint4 r0, r1;
  auto loadB = [&](int t){
    int k0 = kbase + t*32;
    { int col = tid >> 2, j = tid & 3; r0 = *(const uint4*)(Bm + col*32768 + k0 + j*8); }
    { int cI = tid + 256; int col = cI >> 2, j = cI & 3; r1 = *(const uint4*)(Bm + col*32768 + k0 + j*8); }
  };
  auto writeB = [&](int buf){
    { int col = tid >> 2, j = tid & 3; *(uint4*)((char*)b_s[buf] + col*64 + ((j*16) ^ swz64((u32)col))) = r0; }
    { int cI = tid + 256; int col = cI >> 2, j = cI & 3; *(uint4*)((char*)b_s[buf] + col*64 + ((j*16) ^ swz64((u32)col))) = r1; }
  };

  loadB(0); writeB(0);
  __syncthreads();

  f32x4 acc[2][4];
  #pragma unroll
  for (int i = 0; i < 2; ++i)
    #pragma unroll
    for (int j = 0; j < 4; ++j) acc[i][j] = f32x4{0.f,0.f,0.f,0.f};

  int cur_a = -1; float pv[2] = {0.f, 0.f};
  for (int t = 0; t < 128; ++t) {
    int buf = t & 1;
    int k0 = kbase + t*32;
    int a = k0 / 160, c0 = k0 % 160;
    if (t < 127) loadB(t+1);
    if (a != cur_a) { cur_a = a;
      #pragma unroll
      for (int mf = 0; mf < 2; ++mf) {
        int row = wr*32 + mf*16 + (lane & 15);
        pv[mf] = b2f(pg[(b0+row)*208 + a]);
      }
    }
    short8 af[2];
    #pragma unroll
    for (int mf = 0; mf < 2; ++mf) {
      u32 row = wr*32 + mf*16 + (lane & 15);
      uint4 qv = *(const uint4*)((const char*)q_s + row*512 + (((u32)(c0 + 8*(lane>>4))*2u) ^ swz512(row)));
      u32 d[4];
      #pragma unroll
      for (int i2 = 0; i2 < 4; ++i2) {
        u32 qq = (&qv.x)[i2];
        float lo = u2f(qq << 16) * pv[mf];
        float hi = u2f(qq & 0xffff0000u) * pv[mf];
        d[i2] = cvtpk(lo, hi);
      }
      U16x8 u; u.u = make_uint4(d[0], d[1], d[2], d[3]);
      af[mf] = u.s;
    }
    short8 bfr[4];
    #pragma unroll
    for (int nf = 0; nf < 4; ++nf) {
      u32 col = wc*64 + nf*16 + (lane & 15);
      U16x8 u; u.u = *(const uint4*)((const char*)b_s[buf] + col*64 + ((16*(lane>>4)) ^ swz64(col)));
      bfr[nf] = u.s;
    }
    #pragma unroll
    for (int mf = 0; mf < 2; ++mf)
      #pragma unroll
      for (int nf = 0; nf < 4; ++nf)
        acc[mf][nf] = __builtin_amdgcn_mfma_f32_16x16x32_bf16(af[mf], bfr[nf], acc[mf][nf], 0, 0, 0);
    if (t < 127) writeB(buf ^ 1);
    __syncthreads();
  }

  #pragma unroll
  for (int mf = 0; mf < 2; ++mf)
    #pragma unroll
    for (int nf = 0; nf < 4; ++nf) {
      int colg = wc*64 + nf*16 + (lane & 15);
      #pragma unroll
      for (int r = 0; r < 4; ++r) {
        int m = b0 + wr*32 + mf*16 + (lane>>4)*4 + r;
        atomicAdd(&zn[m*128 + colg], acc[mf][nf][r]);
      }
    }
}

// ---------------- yt = zn @ C.T + (ut*dt) @ D.T ----------------
__global__ __launch_bounds__(256) void yt_kernel(
    const float* __restrict__ zn, const float* __restrict__ ut, const float* __restrict__ dt,
    const float* __restrict__ C, const float* __restrict__ D, float* __restrict__ yt)
{
  __shared__ float zn_s[32][132];
  __shared__ float C_s[50][132];
  __shared__ float D_s[50][16];
  __shared__ float ud_s[32][16];
  int tid = threadIdx.x; int b0 = blockIdx.x * 32;
  for (int i = tid; i < 32*128; i += 256) { int r = i >> 7, j = i & 127; zn_s[r][j] = zn[(b0+r)*128 + j]; }
  for (int i = tid; i < 50*128; i += 256) { int r = i >> 7, j = i & 127; C_s[r][j] = C[i]; }
  for (int i = tid; i < 50*16;  i += 256) { D_s[i>>4][i&15] = D[i]; }
  for (int i = tid; i < 32*16;  i += 256) { int r = i >> 4, u = i & 15; ud_s[r][u] = ut[(b0+r)*16 + u] * dt[b0+r]; }
  __syncthreads();
  for (int idx = tid; idx < 1600; idx += 256) {
    int o = idx >> 5, r = idx & 31;
    float acc = 0.f;
    #pragma unroll 4
    for (int j = 0; j < 128; ++j) acc += C_s[o][j] * zn_s[r][j];
    #pragma unroll
    for (int u = 0; u < 16; ++u)  acc += D_s[o][u] * ud_s[r][u];
    yt[(b0+r)*50 + o] = acc;
  }
}

extern "C" void kernel_launch(void* const* d_in, const int* in_sizes, int n_in,
                              void* d_out, int out_size, void* d_ws, size_t ws_size,
                              hipStream_t stream) {
  (void)in_sizes; (void)n_in; (void)out_size;
  if (ws_size < (size_t)WS_NEED) return;   // defensive: never write OOB scratch
  const float* z_dyn = (const float*)d_in[0];
  const float* z_st  = (const float*)d_in[1];
  const float* dt    = (const float*)d_in[2];
  const float* ut    = (const float*)d_in[3];
  const float* W1 = (const float*)d_in[4];  const float* b1 = (const float*)d_in[5];
  const float* g1 = (const float*)d_in[6];  const float* be1 = (const float*)d_in[7];
  const float* W2 = (const float*)d_in[8];  const float* b2 = (const float*)d_in[9];
  const float* g2 = (const float*)d_in[10]; const float* be2 = (const float*)d_in[11];
  const float* W3 = (const float*)d_in[12]; const float* b3 = (const float*)d_in[13];
  const float* WK = (const float*)d_in[14]; const float* bK = (const float*)d_in[15];
  const float* WL = (const float*)d_in[16]; const float* bL = (const float*)d_in[17];
  const float* C  = (const float*)d_in[18]; const float* D  = (const float*)d_in[19];

  char* ws = (char*)d_ws;
  u16* Xb  = (u16*)(ws + OFF_X);
  u16* W1b = (u16*)(ws + OFF_W1);
  u16* W2b = (u16*)(ws + OFF_W2);
  u16* W3b = (u16*)(ws + OFF_W3);
  u16* Bm  = (u16*)(ws + OFF_BM);
  u16* qg  = (u16*)(ws + OFF_Q);
  u16* pg  = (u16*)(ws + OFF_P);
  float* t1 = (float*)(ws + OFF_T1);
  float* t2 = (float*)(ws + OFF_T2);
  float* S1a = (float*)(ws + OFF_ST);
  float* S2a = S1a + 256;
  float* S1b = S1a + 512;
  float* S2b = S1a + 768;

  float* zn = (float*)d_out;
  float* yt = (float*)d_out + 4096*128;

  hipMemsetAsync(d_out, 0, 4096*128*sizeof(float), stream);     // zn accumulates via atomics
  hipMemsetAsync(ws + OFF_ST, 0, 4096, stream);                 // stats accumulate via atomics

  prep_misc<<<1024, 256, 0, stream>>>(z_dyn, z_st, dt, ut, W1, W2, W3, Xb, qg, pg, W1b, W2b, W3b);
  prep_bmat<<<2048, 256, 0, stream>>>(WK, bK, WL, bL, Bm);

  gemm_mlp<0><<<dim3(32,4), 256, 0, stream>>>(Xb, nullptr, W1b, 224, 7,
      nullptr, nullptr, nullptr, nullptr, b1, t1, nullptr);
  stats_k<<<64, 256, 0, stream>>>(t1, S1a, S2a);
  gemm_mlp<1><<<dim3(32,4), 256, 0, stream>>>(nullptr, t1, W2b, 256, 8,
      S1a, S2a, g1, be1, b2, t2, nullptr);
  stats_k<<<64, 256, 0, stream>>>(t2, S1b, S2b);
  gemm_mlp<2><<<dim3(32,3), 256, 0, stream>>>(nullptr, t2, W3b, 256, 8,
      S1b, S2b, g2, be2, b3, nullptr, pg);

  big_gemm<<<dim3(64,8), 256, 0, stream>>>(Bm, qg, pg, zn);
  yt_kernel<<<128, 256, 0, stream>>>(zn, ut, dt, C, D, yt);
}